// Round 19
// baseline (582.039 us; speedup 1.0000x reference)
//
#include <hip/hip_runtime.h>
#include <hip/hip_bf16.h>

typedef __attribute__((ext_vector_type(8)))  short short8v;
typedef __attribute__((ext_vector_type(16))) float f32x16;
typedef __attribute__((ext_vector_type(4)))  int   int4v;

// ===========================================================================
// Encoder weight prepack for MFMA (split bf16 hi/lo).
// ===========================================================================
template<int CIN>
__global__ __launch_bounds__(256) void pack_we(
    const float* __restrict__ w, __hip_bfloat16* __restrict__ whi,
    __hip_bfloat16* __restrict__ wlo, int total)
{
    const int NCHUNK = CIN / 16;
    int idx = blockIdx.x * 256 + threadIdx.x;
    if (idx >= total) return;
    int m  = idx & 31;
    int h  = (idx >> 5) & 1;
    int s  = (idx >> 6) % 9;
    int c  = (idx / 576) % NCHUNK;
    int cg = idx / (576 * NCHUNK);
    int co = cg * 32 + m;
    unsigned short vh[8], vl[8];
    #pragma unroll
    for (int j = 0; j < 8; ++j) {
        int ci = c * 16 + h * 8 + j;
        float x = (co < 36) ? w[(long)co * CIN * 9 + ci * 9 + s] : 0.f;
        __hip_bfloat16 xh = __float2bfloat16(x);
        float rem = x - __bfloat162float(xh);
        __hip_bfloat16 xl = __float2bfloat16(rem);
        vh[j] = *(unsigned short*)&xh;
        vl[j] = *(unsigned short*)&xl;
    }
    *(int4v*)(whi + (long)idx * 8) = *(int4v*)vh;
    *(int4v*)(wlo + (long)idx * 8) = *(int4v*)vl;
}

// ===========================================================================
// feat_hl: fp32 NCHW -> chunk-major interleaved bf16 hi/lo.
// ===========================================================================
template<int CIN, int PXB>
__global__ __launch_bounds__(256) void feat_hl(
    const float* __restrict__ f, __hip_bfloat16* __restrict__ fhl,
    int HW, int npx)
{
    const int NCHUNK = CIN / 16;
    __shared__ float t[CIN][PXB];
    const int p0 = blockIdx.x * PXB;

    for (int i = threadIdx.x; i < CIN * PXB; i += 256) {
        int ci = i / PXB, px = i % PXB;
        int p = p0 + px;
        float v = 0.f;
        if (p < npx) {
            int b = p / HW, r = p - b * HW;
            v = f[((long)b * CIN + ci) * HW + r];
        }
        t[ci][px] = v;
    }
    __syncthreads();

    for (int i = threadIdx.x; i < PXB * NCHUNK * 4; i += 256) {
        int q  = i & 3;
        int px = (i >> 2) % PXB;
        int c  = i / (4 * PXB);
        int p = p0 + px;
        if (p >= npx) continue;
        const bool lo = (q >= 2);
        const int ch0 = c * 16 + (q & 1) * 8;
        unsigned short v[8];
        #pragma unroll
        for (int j = 0; j < 8; ++j) {
            float x = t[ch0 + j][px];
            __hip_bfloat16 xh = __float2bfloat16(x);
            if (lo) {
                float rem = x - __bfloat162float(xh);
                xh = __float2bfloat16(rem);
            }
            v[j] = *(unsigned short*)&xh;
        }
        *(int4v*)(fhl + ((long)c * npx + p) * 32 + q * 8) = *(int4v*)v;
    }
}

// ===========================================================================
// MFMA encoder, chunk-major staged, DOUBLE-BUFFERED LDS + reg prefetch:
// one barrier per chunk (write lands in the other buffer, provably quiescent
// past the prior barrier). MFMA core verified R12-R18 (absmax 0.047).
// ===========================================================================
template<int CIN>
__global__ __launch_bounds__(256) void enc_mfma_cl(
    const __hip_bfloat16* __restrict__ fhl,  // [chunk][npx][32]
    const __hip_bfloat16* __restrict__ whi,
    const __hip_bfloat16* __restrict__ wlo,
    const float* __restrict__ bn_s, const float* __restrict__ bn_b,
    const float* __restrict__ thr, const float* __restrict__ beta_raw,
    __hip_bfloat16* __restrict__ avg,        // [16][H][W][40]
    int H, int W, int tiles_x)
{
    const int NCHUNK = CIN / 16;
    __shared__ __align__(16) short sbuf[2][324 * 48];

    const int tid = threadIdx.x;
    const int b   = blockIdx.y;
    const int tx0 = (blockIdx.x % tiles_x) * 16;
    const int ty0 = (blockIdx.x / tiles_x) * 16;
    const long npx = (long)16 * H * W;

    const int lane = tid & 63;
    const int wv   = tid >> 6;
    const int h    = lane >> 5;
    const int n    = lane & 31;
    const int lx   = n & 15;
    const int ly0  = wv * 4 + (n >> 4);

    f32x16 acc[2][2];
    #pragma unroll
    for (int cg = 0; cg < 2; ++cg)
        #pragma unroll
        for (int pf = 0; pf < 2; ++pf)
            #pragma unroll
            for (int k = 0; k < 16; ++k) acc[cg][pf][k] = 0.f;

    const char* aph = (const char*)whi + h * 512 + n * 16;
    const char* apl = (const char*)wlo + h * 512 + n * 16;
    const long  cgstride = (long)NCHUNK * 9216;

    int4v rv[6];

#define ENC_LOAD_CHUNK(CC)                                                  \
    _Pragma("unroll")                                                       \
    for (int k = 0; k < 6; ++k) {                                           \
        const int i = tid + k * 256;                                        \
        rv[k] = (int4v){0, 0, 0, 0};                                        \
        if (i < 1296) {                                                     \
            int p = i >> 2, q = i & 3;                                      \
            int hy = p / 18, hx = p - hy * 18;                              \
            int gy = ty0 + hy - 1, gx = tx0 + hx - 1;                       \
            if (gy >= 0 && gy < H && gx >= 0 && gx < W) {                   \
                long pg = (long)(b * H + gy) * W + gx;                      \
                rv[k] = *(const int4v*)(fhl + ((long)(CC) * npx + pg) * 32 + q * 8); \
            }                                                               \
        }                                                                   \
    }

#define ENC_WRITE_BUF(BUF)                                                  \
    _Pragma("unroll")                                                       \
    for (int k = 0; k < 6; ++k) {                                           \
        const int i = tid + k * 256;                                        \
        if (i < 1296) {                                                     \
            int p = i >> 2, q = i & 3;                                      \
            char* dst = (q < 2) ? (char*)(BUF) + p * 48 + q * 16            \
                                : (char*)((BUF) + 324 * 24) + p * 48 + (q - 2) * 16; \
            *(int4v*)dst = rv[k];                                           \
        }                                                                   \
    }

    // ---- prologue: chunk0 -> buf0; issue chunk1 ----
    ENC_LOAD_CHUNK(0);
    ENC_WRITE_BUF(sbuf[0]);
    if (NCHUNK > 1) { ENC_LOAD_CHUNK(1); }
    __syncthreads();

    for (int c = 0; c < NCHUNK; ++c) {
        const short* hi_t = sbuf[c & 1];
        const short* lo_t = hi_t + 324 * 24;

        const char* ahc = aph + (long)c * 9216;
        const char* alc = apl + (long)c * 9216;
        #pragma unroll
        for (int s = 0; s < 9; ++s) {
            const int dy = s / 3, dx = s % 3;
            const int p0 = (ly0 + dy) * 18 + (lx + dx);
            const int p1 = p0 + 36;
            short8v bh0 = *(const short8v*)((const char*)hi_t + p0 * 48 + h * 16);
            short8v bh1 = *(const short8v*)((const char*)hi_t + p1 * 48 + h * 16);
            short8v bl0 = *(const short8v*)((const char*)lo_t + p0 * 48 + h * 16);
            short8v bl1 = *(const short8v*)((const char*)lo_t + p1 * 48 + h * 16);
            #pragma unroll
            for (int cg = 0; cg < 2; ++cg) {
                short8v af = *(const short8v*)(ahc + cg * cgstride + s * 1024);
                short8v al = *(const short8v*)(alc + cg * cgstride + s * 1024);
                acc[cg][0] = __builtin_amdgcn_mfma_f32_32x32x16_bf16(af, bh0, acc[cg][0], 0, 0, 0);
                acc[cg][0] = __builtin_amdgcn_mfma_f32_32x32x16_bf16(af, bl0, acc[cg][0], 0, 0, 0);
                acc[cg][0] = __builtin_amdgcn_mfma_f32_32x32x16_bf16(al, bh0, acc[cg][0], 0, 0, 0);
                acc[cg][1] = __builtin_amdgcn_mfma_f32_32x32x16_bf16(af, bh1, acc[cg][1], 0, 0, 0);
                acc[cg][1] = __builtin_amdgcn_mfma_f32_32x32x16_bf16(af, bl1, acc[cg][1], 0, 0, 0);
                acc[cg][1] = __builtin_amdgcn_mfma_f32_32x32x16_bf16(al, bh1, acc[cg][1], 0, 0, 0);
            }
        }

        if (c + 1 < NCHUNK) {
            short* nb = sbuf[(c + 1) & 1];
            ENC_WRITE_BUF(nb);                 // vmcnt hidden under MFMA above
            if (c + 2 < NCHUNK) { ENC_LOAD_CHUNK(c + 2); }
            __syncthreads();                    // single barrier per chunk
        }
    }
    __syncthreads();   // all MFMA done before sbuf[0] reuse

    // ---- epilogue: LIF -> LDS transpose -> coalesced 16B stores ----
    short* ob = sbuf[0];
    for (int i = tid; i < 1280; i += 256)
        *(int4v*)((char*)ob + i * 16) = (int4v){0, 0, 0, 0};
    __syncthreads();

    #pragma unroll
    for (int cg = 0; cg < 2; ++cg) {
        #pragma unroll
        for (int r = 0; r < 16; ++r) {
            const int co = (cg << 5) + (r & 3) + ((r >> 2) << 3) + (h << 2);
            if (co < 36) {
                const float sc   = bn_s[co], sb = bn_b[co];
                const float beta = 1.f / (1.f + expf(-beta_raw[co]));
                const float t    = thr[co];
                #pragma unroll
                for (int pf = 0; pf < 2; ++pf) {
                    const int ly = ly0 + pf * 2;
                    float hv = acc[cg][pf][r] * sc + sb;
                    float m = 0.f, c2 = 0.f;
                    #pragma unroll
                    for (int s4 = 0; s4 < 4; ++s4) {
                        m = beta * m + hv;
                        if (m > t) { c2 += 1.f; m -= t; }
                    }
                    __hip_bfloat16 ov = __float2bfloat16(c2 * 0.25f);
                    ob[(ly * 16 + lx) * 40 + co] = *(short*)&ov;
                }
            }
        }
    }
    __syncthreads();

    const long tilebase = ((long)(b * H + ty0) * W + tx0) * 40;
    for (int i = tid; i < 1280; i += 256) {
        int px = i / 5, u = i - px * 5;
        int py2 = px >> 4, px2 = px & 15;
        *(int4v*)(avg + tilebase + ((long)py2 * W + px2) * 40 + u * 8) =
            *(const int4v*)(ob + px * 40 + u * 8);
    }
#undef ENC_LOAD_CHUNK
#undef ENC_WRITE_BUF
}

// ===========================================================================
// MFMA encoder, ci-split partial variant (enc5), double-buffered.
// ===========================================================================
template<int CIN, int CIPER>
__global__ __launch_bounds__(256) void enc_mfma_p(
    const __hip_bfloat16* __restrict__ fhl,
    const __hip_bfloat16* __restrict__ whi,
    const __hip_bfloat16* __restrict__ wlo,
    float* __restrict__ partial,
    int H, int W, int tiles_x)
{
    const int NCH_TOT = CIN / 16;
    const int NCH_PER = CIPER / 16;
    __shared__ __align__(16) short sbuf[2][324 * 48];

    const int tid = threadIdx.x;
    const int b   = blockIdx.y;
    const int cis = blockIdx.z;
    const int tx0 = (blockIdx.x % tiles_x) * 16;
    const int ty0 = (blockIdx.x / tiles_x) * 16;
    const long npx = (long)16 * H * W;

    const int lane = tid & 63;
    const int wv   = tid >> 6;
    const int h    = lane >> 5;
    const int n    = lane & 31;
    const int lx   = n & 15;
    const int ly0  = wv * 4 + (n >> 4);

    f32x16 acc[2][2];
    #pragma unroll
    for (int cg = 0; cg < 2; ++cg)
        #pragma unroll
        for (int pf = 0; pf < 2; ++pf)
            #pragma unroll
            for (int k = 0; k < 16; ++k) acc[cg][pf][k] = 0.f;

    const char* aph = (const char*)whi + h * 512 + n * 16;
    const char* apl = (const char*)wlo + h * 512 + n * 16;
    const long  cgstride = (long)NCH_TOT * 9216;

    int4v rv[6];

#define ENC_LOAD_CHUNK_P(CC)                                                \
    _Pragma("unroll")                                                       \
    for (int k = 0; k < 6; ++k) {                                           \
        const int i = tid + k * 256;                                        \
        rv[k] = (int4v){0, 0, 0, 0};                                        \
        if (i < 1296) {                                                     \
            int p = i >> 2, q = i & 3;                                      \
            int hy = p / 18, hx = p - hy * 18;                              \
            int gy = ty0 + hy - 1, gx = tx0 + hx - 1;                       \
            if (gy >= 0 && gy < H && gx >= 0 && gx < W) {                   \
                long pg = (long)(b * H + gy) * W + gx;                      \
                rv[k] = *(const int4v*)(fhl + ((long)(CC) * npx + pg) * 32 + q * 8); \
            }                                                               \
        }                                                                   \
    }

#define ENC_WRITE_BUF_P(BUF)                                                \
    _Pragma("unroll")                                                       \
    for (int k = 0; k < 6; ++k) {                                           \
        const int i = tid + k * 256;                                        \
        if (i < 1296) {                                                     \
            int p = i >> 2, q = i & 3;                                      \
            char* dst = (q < 2) ? (char*)(BUF) + p * 48 + q * 16            \
                                : (char*)((BUF) + 324 * 24) + p * 48 + (q - 2) * 16; \
            *(int4v*)dst = rv[k];                                           \
        }                                                                   \
    }

    ENC_LOAD_CHUNK_P(cis * NCH_PER);
    ENC_WRITE_BUF_P(sbuf[0]);
    if (NCH_PER > 1) { ENC_LOAD_CHUNK_P(cis * NCH_PER + 1); }
    __syncthreads();

    for (int c = 0; c < NCH_PER; ++c) {
        const int gc = cis * NCH_PER + c;
        const short* hi_t = sbuf[c & 1];
        const short* lo_t = hi_t + 324 * 24;

        const char* ahc = aph + (long)gc * 9216;
        const char* alc = apl + (long)gc * 9216;
        #pragma unroll
        for (int s = 0; s < 9; ++s) {
            const int dy = s / 3, dx = s % 3;
            const int p0 = (ly0 + dy) * 18 + (lx + dx);
            const int p1 = p0 + 36;
            short8v bh0 = *(const short8v*)((const char*)hi_t + p0 * 48 + h * 16);
            short8v bh1 = *(const short8v*)((const char*)hi_t + p1 * 48 + h * 16);
            short8v bl0 = *(const short8v*)((const char*)lo_t + p0 * 48 + h * 16);
            short8v bl1 = *(const short8v*)((const char*)lo_t + p1 * 48 + h * 16);
            #pragma unroll
            for (int cg = 0; cg < 2; ++cg) {
                short8v af = *(const short8v*)(ahc + cg * cgstride + s * 1024);
                short8v al = *(const short8v*)(alc + cg * cgstride + s * 1024);
                acc[cg][0] = __builtin_amdgcn_mfma_f32_32x32x16_bf16(af, bh0, acc[cg][0], 0, 0, 0);
                acc[cg][0] = __builtin_amdgcn_mfma_f32_32x32x16_bf16(af, bl0, acc[cg][0], 0, 0, 0);
                acc[cg][0] = __builtin_amdgcn_mfma_f32_32x32x16_bf16(al, bh0, acc[cg][0], 0, 0, 0);
                acc[cg][1] = __builtin_amdgcn_mfma_f32_32x32x16_bf16(af, bh1, acc[cg][1], 0, 0, 0);
                acc[cg][1] = __builtin_amdgcn_mfma_f32_32x32x16_bf16(af, bl1, acc[cg][1], 0, 0, 0);
                acc[cg][1] = __builtin_amdgcn_mfma_f32_32x32x16_bf16(al, bh1, acc[cg][1], 0, 0, 0);
            }
        }

        if (c + 1 < NCH_PER) {
            short* nb = sbuf[(c + 1) & 1];
            ENC_WRITE_BUF_P(nb);
            if (c + 2 < NCH_PER) { ENC_LOAD_CHUNK_P(gc + 2); }
            __syncthreads();
        }
    }

    const int HW = H * W;
    const long total = (long)16 * 36 * HW;
    #pragma unroll
    for (int cg = 0; cg < 2; ++cg) {
        #pragma unroll
        for (int r = 0; r < 16; ++r) {
            const int co = (cg << 5) + (r & 3) + ((r >> 2) << 3) + (h << 2);
            if (co < 36) {
                #pragma unroll
                for (int pf = 0; pf < 2; ++pf) {
                    const int gy = ty0 + ly0 + pf * 2, gx = tx0 + lx;
                    if (gy < H && gx < W)
                        partial[(long)cis * total + ((long)(b * 36 + co) * HW + gy * W + gx)]
                            = acc[cg][pf][r];
                }
            }
        }
    }
#undef ENC_LOAD_CHUNK_P
#undef ENC_WRITE_BUF_P
}

// ===========================================================================
// Original encoder (fallback path).
// ===========================================================================
template<int CIN, int CIPER, int CICHUNK, int COCHUNK, int TDIM, bool PARTIAL, bool CL>
__global__ __launch_bounds__(TDIM* TDIM) void enc_tiled(
    const float* __restrict__ feat,
    const float* __restrict__ w,
    const float* __restrict__ bn_s, const float* __restrict__ bn_b,
    const float* __restrict__ thr, const float* __restrict__ beta_raw,
    __hip_bfloat16* __restrict__ avg,
    float* __restrict__ partial,
    int H, int W, int tiles_x)
{
    const int TPB  = TDIM * TDIM;
    const int HALOD = TDIM + 2;
    const int NCO  = 36 / COCHUNK;
    __shared__ float fs[CICHUNK][HALOD][HALOD];

    const int tile = blockIdx.x;
    const int b    = blockIdx.y;
    const int coc  = blockIdx.z % NCO;
    const int cis  = blockIdx.z / NCO;
    const int co0  = coc * COCHUNK;
    const int tx0  = (tile % tiles_x) * TDIM;
    const int ty0  = (tile / tiles_x) * TDIM;

    const int tx = threadIdx.x % TDIM;
    const int ty = threadIdx.x / TDIM;
    const int ox = tx0 + tx, oy = ty0 + ty;

    float acc[COCHUNK];
    #pragma unroll
    for (int c = 0; c < COCHUNK; ++c) acc[c] = 0.f;

    const float* fb = feat + (long)b * CIN * H * W;
    const int ci_base = cis * CIPER;

    for (int cc = ci_base; cc < ci_base + CIPER; cc += CICHUNK) {
        for (int i = threadIdx.x; i < CICHUNK * HALOD * HALOD; i += TPB) {
            int ci = i / (HALOD * HALOD);
            int r  = i % (HALOD * HALOD);
            int hy = r / HALOD, hx = r % HALOD;
            int gy = ty0 + hy - 1, gx = tx0 + hx - 1;
            float v = 0.f;
            if (gy >= 0 && gy < H && gx >= 0 && gx < W)
                v = fb[((long)(cc + ci) * H + gy) * W + gx];
            fs[ci][hy][hx] = v;
        }
        __syncthreads();

        for (int ci = 0; ci < CICHUNK; ++ci) {
            float f0 = fs[ci][ty    ][tx], f1 = fs[ci][ty    ][tx+1], f2 = fs[ci][ty    ][tx+2];
            float f3 = fs[ci][ty + 1][tx], f4 = fs[ci][ty + 1][tx+1], f5 = fs[ci][ty + 1][tx+2];
            float f6 = fs[ci][ty + 2][tx], f7 = fs[ci][ty + 2][tx+1], f8 = fs[ci][ty + 2][tx+2];
            const float* wq = w + (long)(cc + ci) * 9;
            #pragma unroll
            for (int j = 0; j < COCHUNK; ++j) {
                const float* ww = wq + (long)(co0 + j) * CIN * 9;
                acc[j] += f0 * ww[0] + f1 * ww[1] + f2 * ww[2]
                        + f3 * ww[3] + f4 * ww[4] + f5 * ww[5]
                        + f6 * ww[6] + f7 * ww[7] + f8 * ww[8];
            }
        }
        __syncthreads();
    }

    if (ox < W && oy < H) {
        if (PARTIAL) {
            #pragma unroll
            for (int j = 0; j < COCHUNK; ++j)
                partial[((((long)cis * 16 + b) * 36 + (co0 + j)) * H + oy) * W + ox] = acc[j];
        } else {
            float cnt[COCHUNK];
            #pragma unroll
            for (int j = 0; j < COCHUNK; ++j) {
                int co = co0 + j;
                float hh   = acc[j] * bn_s[co] + bn_b[co];
                float beta = 1.f / (1.f + expf(-beta_raw[co]));
                float t    = thr[co];
                float m = 0.f, c2 = 0.f;
                #pragma unroll
                for (int s = 0; s < 4; ++s) {
                    m = beta * m + hh;
                    if (m > t) { c2 += 1.f; m -= t; }
                }
                cnt[j] = c2 * 0.25f;
            }
            if (CL) {
                unsigned* dp = (unsigned*)(avg + ((long)(b * H + oy) * W + ox) * 40 + co0);
                #pragma unroll
                for (int j2 = 0; j2 < COCHUNK / 2; ++j2) {
                    __hip_bfloat16 h0 = __float2bfloat16(cnt[2 * j2]);
                    __hip_bfloat16 h1 = __float2bfloat16(cnt[2 * j2 + 1]);
                    unsigned u0 = *(unsigned short*)&h0;
                    unsigned u1 = *(unsigned short*)&h1;
                    dp[j2] = u0 | (u1 << 16);
                }
            } else {
                #pragma unroll
                for (int j = 0; j < COCHUNK; ++j)
                    avg[(((long)b * 36 + (co0 + j)) * H + oy) * W + ox] = __float2bfloat16(cnt[j]);
            }
        }
    }
}

// ===========================================================================
// Combine ci-split partials + BN + LIF + mean -> bf16 avg (CL or NCHW).
// ===========================================================================
template<int SPLITS, bool CL>
__global__ __launch_bounds__(256) void combine_lif(
    const float* __restrict__ partial,
    const float* __restrict__ bn_s, const float* __restrict__ bn_b,
    const float* __restrict__ thr, const float* __restrict__ beta_raw,
    __hip_bfloat16* __restrict__ avg, int H, int W, int total)
{
    int idx = blockIdx.x * 256 + threadIdx.x;
    if (idx >= total) return;
    int HW = H * W;
    int co = (idx / HW) % 36;
    float hh = 0.f;
    #pragma unroll
    for (int s = 0; s < SPLITS; ++s) hh += partial[(long)s * total + idx];
    hh = hh * bn_s[co] + bn_b[co];
    float beta = 1.f / (1.f + expf(-beta_raw[co]));
    float t    = thr[co];
    float m = 0.f, cnt = 0.f;
    #pragma unroll
    for (int s = 0; s < 4; ++s) {
        m = beta * m + hh;
        if (m > t) { cnt += 1.f; m -= t; }
    }
    if (CL) {
        int b = idx / (36 * HW);
        int rem = idx % HW;
        int y = rem / W, x = rem % W;
        avg[((long)(b * H + y) * W + x) * 40 + co] = __float2bfloat16(cnt * 0.25f);
    } else {
        avg[idx] = __float2bfloat16(cnt * 0.25f);
    }
}

// ===========================================================================
// Weight prepack for MFMA decoder.
// ===========================================================================
__global__ __launch_bounds__(256) void pack_w(
    const float* __restrict__ w, __hip_bfloat16* __restrict__ ap, int total)
{
    int idx = blockIdx.x * 256 + threadIdx.x;
    if (idx >= total) return;
    int m  = idx & 31;
    int h  = (idx >> 5) & 1;
    int s  = (idx >> 6) % 23;
    int cg = idx / (23 * 64);
    int o  = 2 * s + h;
    int co = cg * 32 + m;
    unsigned short v[8];
    #pragma unroll
    for (int j = 0; j < 8; ++j) {
        float x = 0.f;
        if (o < 45) {
            int tap = o / 5, oct = o % 5, ci = oct * 8 + j;
            if (ci < 36) x = w[(long)co * 324 + ci * 9 + tap];
        }
        __hip_bfloat16 hv = __float2bfloat16(x);
        v[j] = *(unsigned short*)&hv;
    }
    *(int4v*)(ap + (long)idx * 8) = *(int4v*)v;
}

// ===========================================================================
// MFMA decoder: conv3x3(36->Cout) + BN + SiLU.
// ===========================================================================
template<int COG>
__global__ __launch_bounds__(256) void dec_mfma(
    const __hip_bfloat16* __restrict__ avg_cl,
    const __hip_bfloat16* __restrict__ apack,
    const float* __restrict__ bn_s, const float* __restrict__ bn_b,
    float* __restrict__ out, int Cout, int H, int W, int tiles_x)
{
    __shared__ __hip_bfloat16 tile[12960];

    const int tid    = threadIdx.x;
    const int b      = blockIdx.y;
    const int cgbase = blockIdx.z * COG;
    const int tx0 = (blockIdx.x % tiles_x) * 16;
    const int ty0 = (blockIdx.x / tiles_x) * 16;

    {
        const __hip_bfloat16* ab = avg_cl + (long)b * H * W * 40;
        for (int i = tid; i < 1620; i += 256) {
            int row = i / 90, u = i - row * 90;
            int px = u / 5, un = u - px * 5;
            int gy = ty0 + row - 1, gx = tx0 + px - 1;
            int4v v = {0, 0, 0, 0};
            if (gy >= 0 && gy < H && gx >= 0 && gx < W)
                v = *(const int4v*)(ab + ((long)gy * W + gx) * 40 + un * 8);
            *(int4v*)(tile + (row * 18 + px) * 40 + un * 8) = v;
        }
    }
    __syncthreads();

    const int lane = tid & 63;
    const int wv   = tid >> 6;
    const int h    = lane >> 5;
    const int n    = lane & 31;
    const int lx   = n & 15;
    const int ly0  = wv * 4 + (n >> 4);

    const char* tb  = (const char*)tile;
    const int   bb0 = ((ly0 + 1) * 18 + (lx + 1)) * 80;
    const int   bb1 = bb0 + 2 * 18 * 80;

    const char* ap = (const char*)apack + (long)cgbase * 23552 + h * 512 + n * 16;

    f32x16 acc[COG][2];
    #pragma unroll
    for (int cg = 0; cg < COG; ++cg)
        #pragma unroll
        for (int pf = 0; pf < 2; ++pf)
            #pragma unroll
            for (int k = 0; k < 16; ++k) acc[cg][pf][k] = 0.f;

    #pragma unroll
    for (int s = 0; s < 23; ++s) {
        int o0 = 2 * s;     if (o0 > 44) o0 = 44;
        int o1 = 2 * s + 1; if (o1 > 44) o1 = 44;
        const int C0 = ((o0 / 5) / 3 - 1) * 1440 + ((o0 / 5) % 3 - 1) * 80 + (o0 % 5) * 16;
        const int C1 = ((o1 / 5) / 3 - 1) * 1440 + ((o1 / 5) % 3 - 1) * 80 + (o1 % 5) * 16;
        const int offc = h ? C1 : C0;
        short8v bf0 = *(const short8v*)(tb + (bb0 + offc));
        short8v bf1 = *(const short8v*)(tb + (bb1 + offc));
        #pragma unroll
        for (int cg = 0; cg < COG; ++cg) {
            short8v af = *(const short8v*)(ap + cg * 23552 + s * 1024);
            acc[cg][0] = __builtin_amdgcn_mfma_f32_32x32x16_bf16(af, bf0, acc[cg][0], 0, 0, 0);
            acc[cg][1] = __builtin_amdgcn_mfma_f32_32x32x16_bf16(af, bf1, acc[cg][1], 0, 0, 0);
        }
    }

    #pragma unroll
    for (int cg = 0; cg < COG; ++cg) {
        #pragma unroll
        for (int r = 0; r < 16; ++r) {
            const int co = ((cgbase + cg) << 5) + (r & 3) + ((r >> 2) << 3) + (h << 2);
            const float sc = bn_s[co], bc = bn_b[co];
            #pragma unroll
            for (int pf = 0; pf < 2; ++pf) {
                const int ly = ly0 + pf * 2;
                const int gy = ty0 + ly, gx = tx0 + lx;
                float v = acc[cg][pf][r] * sc + bc;
                v = v / (1.f + __expf(-v));
                if (gy < H && gx < W)
                    out[(((long)b * Cout + co) * H + gy) * W + gx] = v;
            }
        }
    }
}

// ===========================================================================
// Fallback decoder (VALU, NCHW avg).
// ===========================================================================
template<int COCHUNK, int TDIM>
__global__ __launch_bounds__(TDIM* TDIM) void dec_tiled(
    const __hip_bfloat16* __restrict__ avg,
    const float* __restrict__ w,
    const float* __restrict__ bn_s, const float* __restrict__ bn_b,
    float* __restrict__ out,
    int Cout, int H, int W, int tiles_x)
{
    const int CIN = 36;
    const int TPB = TDIM * TDIM;
    const int HALOD = TDIM + 2;
    __shared__ float fs[CIN][HALOD][HALOD];

    const int tile = blockIdx.x;
    const int b    = blockIdx.y;
    const int co0  = blockIdx.z * COCHUNK;
    const int tx0  = (tile % tiles_x) * TDIM;
    const int ty0  = (tile / tiles_x) * TDIM;

    const int tx = threadIdx.x % TDIM;
    const int ty = threadIdx.x / TDIM;
    const int ox = tx0 + tx, oy = ty0 + ty;

    const __hip_bfloat16* ab = avg + (long)b * CIN * H * W;

    for (int i = threadIdx.x; i < CIN * HALOD * HALOD; i += TPB) {
        int ci = i / (HALOD * HALOD);
        int r  = i % (HALOD * HALOD);
        int hy = r / HALOD, hx = r % HALOD;
        int gy = ty0 + hy - 1, gx = tx0 + hx - 1;
        float v = 0.f;
        if (gy >= 0 && gy < H && gx >= 0 && gx < W)
            v = __bfloat162float(ab[((long)ci * H + gy) * W + gx]);
        fs[ci][hy][hx] = v;
    }
    __syncthreads();

    float acc[COCHUNK];
    #pragma unroll
    for (int j = 0; j < COCHUNK; ++j) acc[j] = 0.f;

    for (int ci = 0; ci < CIN; ++ci) {
        float f0 = fs[ci][ty    ][tx], f1 = fs[ci][ty    ][tx+1], f2 = fs[ci][ty    ][tx+2];
        float f3 = fs[ci][ty + 1][tx], f4 = fs[ci][ty + 1][tx+1], f5 = fs[ci][ty + 1][tx+2];
        float f6 = fs[ci][ty + 2][tx], f7 = fs[ci][ty + 2][tx+1], f8 = fs[ci][ty + 2][tx+2];
        #pragma unroll
        for (int j = 0; j < COCHUNK; ++j) {
            const float* ww = w + ((long)(co0 + j) * CIN + ci) * 9;
            acc[j] += f0 * ww[0] + f1 * ww[1] + f2 * ww[2]
                    + f3 * ww[3] + f4 * ww[4] + f5 * ww[5]
                    + f6 * ww[6] + f7 * ww[7] + f8 * ww[8];
        }
    }

    if (ox < W && oy < H) {
        #pragma unroll
        for (int j = 0; j < COCHUNK; ++j) {
            int co = co0 + j;
            float v = acc[j] * bn_s[co] + bn_b[co];
            out[(((long)b * Cout + co) * H + oy) * W + ox] = v / (1.f + expf(-v));
        }
    }
}

// ===========================================================================
extern "C" void kernel_launch(void* const* d_in, const int* in_sizes, int n_in,
                              void* d_out, int out_size, void* d_ws, size_t ws_size,
                              hipStream_t stream)
{
    const int B = 16;
    const int C[3] = {64, 128, 256};
    const int S[3] = {160, 80, 40};

    float* out = (float*)d_out;
    long out_off[3]; long off = 0;
    for (int l = 0; l < 3; ++l) { out_off[l] = off; off += (long)B * C[l] * S[l] * S[l]; }

    // ---- workspace layout (bytes) ----
    const long avgcl_bytes[3] = {32768000L, 8192000L, 2048000L};
    long avgcl_off[3]; long boff = 0;
    for (int l = 0; l < 3; ++l) { avgcl_off[l] = boff; boff += avgcl_bytes[l]; }
    const long avgcl_total = boff;
    const long ap_bytes[3] = {47104L, 94208L, 188416L};
    long ap_off[3];
    for (int l = 0; l < 3; ++l) { ap_off[l] = boff; boff += ap_bytes[l]; }
    const long we_bytes[3] = {73728L, 147456L, 294912L};
    long wehi_off[3], welo_off[3];
    for (int l = 0; l < 3; ++l) { wehi_off[l] = boff; boff += we_bytes[l];
                                  welo_off[l] = boff; boff += we_bytes[l]; }
    const long part5_off = boff;
    const long part5_bytes = 4L * B * 36 * 1600 * 4;
    boff += part5_bytes;
    const size_t need_full = (size_t)boff;
    const size_t need_min  = (size_t)part5_off;
    const long fhl_bytes[3] = {104857600L, 52428800L, 26214400L};
    long fhl_off[3];
    for (int l = 0; l < 2; ++l) { fhl_off[l] = boff; boff += fhl_bytes[l]; }
    const size_t need_cl = (size_t)boff;
    fhl_off[2] = boff; boff += fhl_bytes[2];
    const size_t need_cl5 = (size_t)boff;

    char* wsb = (char*)d_ws;

    if (ws_size >= need_min) {
        const bool split5  = ws_size >= need_full;
        const bool use_cl  = ws_size >= need_cl;
        const bool use_cl5 = ws_size >= need_cl5;
        hipMemsetAsync(wsb, 0, avgcl_total, stream);

        for (int l = 0; l < 3; ++l) {
            const float* dec_w = (const float*)d_in[9 * l + 6];
            int total = (C[l] / 32) * 23 * 2 * 32;
            pack_w<<<(total + 255) / 256, 256, 0, stream>>>(
                dec_w, (__hip_bfloat16*)(wsb + ap_off[l]), total);
        }
        {
            const float* enc_w3 = (const float*)d_in[1];
            int total = 2 * (64 / 16) * 9 * 2 * 32;
            pack_we<64><<<(total + 255) / 256, 256, 0, stream>>>(
                enc_w3, (__hip_bfloat16*)(wsb + wehi_off[0]),
                (__hip_bfloat16*)(wsb + welo_off[0]), total);
        }
        {
            const float* enc_w4 = (const float*)d_in[10];
            int total = 2 * (128 / 16) * 9 * 2 * 32;
            pack_we<128><<<(total + 255) / 256, 256, 0, stream>>>(
                enc_w4, (__hip_bfloat16*)(wsb + wehi_off[1]),
                (__hip_bfloat16*)(wsb + welo_off[1]), total);
        }
        if (use_cl5) {
            const float* enc_w5 = (const float*)d_in[19];
            int total = 2 * (256 / 16) * 9 * 2 * 32;
            pack_we<256><<<(total + 255) / 256, 256, 0, stream>>>(
                enc_w5, (__hip_bfloat16*)(wsb + wehi_off[2]),
                (__hip_bfloat16*)(wsb + welo_off[2]), total);
        }
        if (use_cl) {
            {
                int HW = 160 * 160, npx = B * HW;
                feat_hl<64, 64><<<(npx + 63) / 64, 256, 0, stream>>>(
                    (const float*)d_in[0], (__hip_bfloat16*)(wsb + fhl_off[0]), HW, npx);
            }
            {
                int HW = 80 * 80, npx = B * HW;
                feat_hl<128, 64><<<(npx + 63) / 64, 256, 0, stream>>>(
                    (const float*)d_in[9], (__hip_bfloat16*)(wsb + fhl_off[1]), HW, npx);
            }
        }
        if (use_cl5) {
            int HW = 40 * 40, npx = B * HW;
            feat_hl<256, 32><<<(npx + 31) / 32, 256, 0, stream>>>(
                (const float*)d_in[18], (__hip_bfloat16*)(wsb + fhl_off[2]), HW, npx);
        }

        for (int l = 0; l < 3; ++l) {
            const int base = 9 * l;
            const float* feat     = (const float*)d_in[base + 0];
            const float* enc_w    = (const float*)d_in[base + 1];
            const float* enc_bn_s = (const float*)d_in[base + 2];
            const float* enc_bn_b = (const float*)d_in[base + 3];
            const float* enc_thr  = (const float*)d_in[base + 4];
            const float* enc_beta = (const float*)d_in[base + 5];
            const float* dec_bn_s = (const float*)d_in[base + 7];
            const float* dec_bn_b = (const float*)d_in[base + 8];

            const int Hs = S[l], Wsz = S[l];
            __hip_bfloat16* avg_cl = (__hip_bfloat16*)(wsb + avgcl_off[l]);
            const __hip_bfloat16* ap = (const __hip_bfloat16*)(wsb + ap_off[l]);
            float* r = out + out_off[l];

            if (l == 0) {
                dim3 eg(100, B);
                if (use_cl)
                    enc_mfma_cl<64><<<eg, 256, 0, stream>>>(
                        (const __hip_bfloat16*)(wsb + fhl_off[0]),
                        (const __hip_bfloat16*)(wsb + wehi_off[0]),
                        (const __hip_bfloat16*)(wsb + welo_off[0]),
                        enc_bn_s, enc_bn_b, enc_thr, enc_beta, avg_cl, Hs, Wsz, 10);
                else
                    enc_tiled<64, 64, 16, 12, 16, false, true><<<dim3(100, B, 3), 256, 0, stream>>>(
                        feat, enc_w, enc_bn_s, enc_bn_b, enc_thr, enc_beta, avg_cl, nullptr, Hs, Wsz, 10);
                dim3 dg(100, B, 1);
                dec_mfma<2><<<dg, 256, 0, stream>>>(avg_cl, ap, dec_bn_s, dec_bn_b, r, 64, Hs, Wsz, 10);
            } else if (l == 1) {
                dim3 eg(25, B);
                if (use_cl)
                    enc_mfma_cl<128><<<eg, 256, 0, stream>>>(
                        (const __hip_bfloat16*)(wsb + fhl_off[1]),
                        (const __hip_bfloat16*)(wsb + wehi_off[1]),
                        (const __hip_bfloat16*)(wsb + welo_off[1]),
                        enc_bn_s, enc_bn_b, enc_thr, enc_beta, avg_cl, Hs, Wsz, 5);
                else
                    enc_tiled<128, 128, 16, 12, 16, false, true><<<dim3(25, B, 3), 256, 0, stream>>>(
                        feat, enc_w, enc_bn_s, enc_bn_b, enc_thr, enc_beta, avg_cl, nullptr, Hs, Wsz, 5);
                dim3 dg(25, B, 2);
                dec_mfma<2><<<dg, 256, 0, stream>>>(avg_cl, ap, dec_bn_s, dec_bn_b, r, 128, Hs, Wsz, 5);
            } else {
                if (use_cl5) {
                    float* partial5 = (float*)(wsb + part5_off);
                    dim3 eg(9, B, 4);
                    enc_mfma_p<256, 64><<<eg, 256, 0, stream>>>(
                        (const __hip_bfloat16*)(wsb + fhl_off[2]),
                        (const __hip_bfloat16*)(wsb + wehi_off[2]),
                        (const __hip_bfloat16*)(wsb + welo_off[2]),
                        partial5, Hs, Wsz, 3);
                    int total = B * 36 * Hs * Wsz;
                    combine_lif<4, true><<<(total + 255) / 256, 256, 0, stream>>>(
                        partial5, enc_bn_s, enc_bn_b, enc_thr, enc_beta, avg_cl, Hs, Wsz, total);
                } else if (split5) {
                    float* partial5 = (float*)(wsb + part5_off);
                    dim3 eg(25, B, 12);
                    enc_tiled<256, 64, 16, 12, 8, true, true><<<eg, 64, 0, stream>>>(
                        feat, enc_w, enc_bn_s, enc_bn_b, enc_thr, enc_beta, nullptr, partial5, Hs, Wsz, 5);
                    int total = B * 36 * Hs * Wsz;
                    combine_lif<4, true><<<(total + 255) / 256, 256, 0, stream>>>(
                        partial5, enc_bn_s, enc_bn_b, enc_thr, enc_beta, avg_cl, Hs, Wsz, total);
                } else {
                    dim3 eg(25, B, 3);
                    enc_tiled<256, 256, 16, 12, 8, false, true><<<eg, 64, 0, stream>>>(
                        feat, enc_w, enc_bn_s, enc_bn_b, enc_thr, enc_beta, avg_cl, nullptr, Hs, Wsz, 5);
                }
                dim3 dg(9, B, 4);
                dec_mfma<2><<<dg, 256, 0, stream>>>(avg_cl, ap, dec_bn_s, dec_bn_b, r, 256, Hs, Wsz, 3);
            }
        }
    } else {
        // ================= FALLBACK (NCHW, VALU decoder) =================
        __hip_bfloat16* ws = (__hip_bfloat16*)d_ws;
        long avg_off2[3]; long eoff = 0;
        for (int l = 0; l < 3; ++l) { avg_off2[l] = eoff; eoff += (long)B * 36 * S[l] * S[l]; }
        float* partial5 = (float*)(ws + ((eoff + 7) & ~7L));
        const long part5f = 4L * B * 36 * 40 * 40;
        const size_t old_need = (size_t)((eoff + 7) & ~7L) * 2 + part5f * 4;
        const bool split5 = ws_size >= old_need;

        for (int l = 0; l < 3; ++l) {
            const int base = 9 * l;
            const float* feat     = (const float*)d_in[base + 0];
            const float* enc_w    = (const float*)d_in[base + 1];
            const float* enc_bn_s = (const float*)d_in[base + 2];
            const float* enc_bn_b = (const float*)d_in[base + 3];
            const float* enc_thr  = (const float*)d_in[base + 4];
            const float* enc_beta = (const float*)d_in[base + 5];
            const float* dec_w    = (const float*)d_in[base + 6];
            const float* dec_bn_s = (const float*)d_in[base + 7];
            const float* dec_bn_b = (const float*)d_in[base + 8];

            const int Hs = S[l], Wsz = S[l], Cl = C[l];
            __hip_bfloat16* avg = ws + avg_off2[l];
            float* r = out + out_off[l];

            if (l == 0) {
                dim3 eg(100, B, 3);
                enc_tiled<64, 64, 16, 12, 16, false, false><<<eg, 256, 0, stream>>>(
                    feat, enc_w, enc_bn_s, enc_bn_b, enc_thr, enc_beta, avg, nullptr, Hs, Wsz, 10);
                dim3 dg(100, B, 2);
                dec_tiled<32, 16><<<dg, 256, 0, stream>>>(avg, dec_w, dec_bn_s, dec_bn_b, r, Cl, Hs, Wsz, 10);
            } else if (l == 1) {
                dim3 eg(25, B, 3);
                enc_tiled<128, 128, 16, 12, 16, false, false><<<eg, 256, 0, stream>>>(
                    feat, enc_w, enc_bn_s, enc_bn_b, enc_thr, enc_beta, avg, nullptr, Hs, Wsz, 5);
                dim3 dg(25, B, 4);
                dec_tiled<32, 16><<<dg, 256, 0, stream>>>(avg, dec_w, dec_bn_s, dec_bn_b, r, Cl, Hs, Wsz, 5);
            } else {
                if (split5) {
                    dim3 eg(25, B, 12);
                    enc_tiled<256, 64, 16, 12, 8, true, false><<<eg, 64, 0, stream>>>(
                        feat, enc_w, enc_bn_s, enc_bn_b, enc_thr, enc_beta, nullptr, partial5, Hs, Wsz, 5);
                    int total = B * 36 * Hs * Wsz;
                    combine_lif<4, false><<<(total + 255) / 256, 256, 0, stream>>>(
                        partial5, enc_bn_s, enc_bn_b, enc_thr, enc_beta, avg, Hs, Wsz, total);
                } else {
                    dim3 eg(25, B, 3);
                    enc_tiled<256, 256, 16, 12, 8, false, false><<<eg, 64, 0, stream>>>(
                        feat, enc_w, enc_bn_s, enc_bn_b, enc_thr, enc_beta, avg, nullptr, Hs, Wsz, 5);
                }
                dim3 dg(25, B, 16);
                dec_tiled<16, 8><<<dg, 64, 0, stream>>>(avg, dec_w, dec_bn_s, dec_bn_b, r, Cl, Hs, Wsz, 5);
            }
        }
    }
}

// Round 20
// 570.982 us; speedup vs baseline: 1.0194x; 1.0194x over previous
//
#include <hip/hip_runtime.h>
#include <hip/hip_bf16.h>

typedef __attribute__((ext_vector_type(8)))  short short8v;
typedef __attribute__((ext_vector_type(16))) float f32x16;
typedef __attribute__((ext_vector_type(4)))  int   int4v;

// ===========================================================================
// Encoder weight prepack for MFMA (split bf16 hi/lo).
// ===========================================================================
template<int CIN>
__global__ __launch_bounds__(256) void pack_we(
    const float* __restrict__ w, __hip_bfloat16* __restrict__ whi,
    __hip_bfloat16* __restrict__ wlo, int total)
{
    const int NCHUNK = CIN / 16;
    int idx = blockIdx.x * 256 + threadIdx.x;
    if (idx >= total) return;
    int m  = idx & 31;
    int h  = (idx >> 5) & 1;
    int s  = (idx >> 6) % 9;
    int c  = (idx / 576) % NCHUNK;
    int cg = idx / (576 * NCHUNK);
    int co = cg * 32 + m;
    unsigned short vh[8], vl[8];
    #pragma unroll
    for (int j = 0; j < 8; ++j) {
        int ci = c * 16 + h * 8 + j;
        float x = (co < 36) ? w[(long)co * CIN * 9 + ci * 9 + s] : 0.f;
        __hip_bfloat16 xh = __float2bfloat16(x);
        float rem = x - __bfloat162float(xh);
        __hip_bfloat16 xl = __float2bfloat16(rem);
        vh[j] = *(unsigned short*)&xh;
        vl[j] = *(unsigned short*)&xl;
    }
    *(int4v*)(whi + (long)idx * 8) = *(int4v*)vh;
    *(int4v*)(wlo + (long)idx * 8) = *(int4v*)vl;
}

// ===========================================================================
// feat_hl: fp32 NCHW -> chunk-major interleaved bf16 hi/lo:
//   fhl[((chunk * npx) + p) * 32 + q*8],  q = {hi0-7, hi8-15, lo0-7, lo8-15}
// ===========================================================================
template<int CIN, int PXB>
__global__ __launch_bounds__(256) void feat_hl(
    const float* __restrict__ f, __hip_bfloat16* __restrict__ fhl,
    int HW, int npx)
{
    const int NCHUNK = CIN / 16;
    __shared__ float t[CIN][PXB];
    const int p0 = blockIdx.x * PXB;

    for (int i = threadIdx.x; i < CIN * PXB; i += 256) {
        int ci = i / PXB, px = i % PXB;
        int p = p0 + px;
        float v = 0.f;
        if (p < npx) {
            int b = p / HW, r = p - b * HW;
            v = f[((long)b * CIN + ci) * HW + r];
        }
        t[ci][px] = v;
    }
    __syncthreads();

    for (int i = threadIdx.x; i < PXB * NCHUNK * 4; i += 256) {
        int q  = i & 3;
        int px = (i >> 2) % PXB;
        int c  = i / (4 * PXB);
        int p = p0 + px;
        if (p >= npx) continue;
        const bool lo = (q >= 2);
        const int ch0 = c * 16 + (q & 1) * 8;
        unsigned short v[8];
        #pragma unroll
        for (int j = 0; j < 8; ++j) {
            float x = t[ch0 + j][px];
            __hip_bfloat16 xh = __float2bfloat16(x);
            if (lo) {
                float rem = x - __bfloat162float(xh);
                xh = __float2bfloat16(rem);
            }
            v[j] = *(unsigned short*)&xh;
        }
        *(int4v*)(fhl + ((long)c * npx + p) * 32 + q * 8) = *(int4v*)v;
    }
}

// ===========================================================================
// MFMA encoder, chunk-major-staged, reg-prefetch pipelined (R18-exact,
// session best: enc3 141us, MfmaUtil 26%). Single-buffered LDS, 2 barriers
// per chunk. MFMA core + LDS layout in-situ verified R12-R18 (absmax 0.047).
// (R19's double-buffer variant regressed: occupancy is register-bound, so
// halving barriers shifted the stall without removing it.)
// ===========================================================================
template<int CIN>
__global__ __launch_bounds__(256) void enc_mfma_cl(
    const __hip_bfloat16* __restrict__ fhl,  // [chunk][npx][32]
    const __hip_bfloat16* __restrict__ whi,
    const __hip_bfloat16* __restrict__ wlo,
    const float* __restrict__ bn_s, const float* __restrict__ bn_b,
    const float* __restrict__ thr, const float* __restrict__ beta_raw,
    __hip_bfloat16* __restrict__ avg,        // [16][H][W][40]
    int H, int W, int tiles_x)
{
    const int NCHUNK = CIN / 16;
    __shared__ __align__(16) short sbuf[324 * 48];
    short* hi_t = sbuf;
    short* lo_t = sbuf + 324 * 24;

    const int tid = threadIdx.x;
    const int b   = blockIdx.y;
    const int tx0 = (blockIdx.x % tiles_x) * 16;
    const int ty0 = (blockIdx.x / tiles_x) * 16;
    const long npx = (long)16 * H * W;

    const int lane = tid & 63;
    const int wv   = tid >> 6;
    const int h    = lane >> 5;
    const int n    = lane & 31;
    const int lx   = n & 15;
    const int ly0  = wv * 4 + (n >> 4);

    f32x16 acc[2][2];
    #pragma unroll
    for (int cg = 0; cg < 2; ++cg)
        #pragma unroll
        for (int pf = 0; pf < 2; ++pf)
            #pragma unroll
            for (int k = 0; k < 16; ++k) acc[cg][pf][k] = 0.f;

    const char* aph = (const char*)whi + h * 512 + n * 16;
    const char* apl = (const char*)wlo + h * 512 + n * 16;
    const long  cgstride = (long)NCHUNK * 9216;

    int4v rv[6];
    // ---- prologue: load chunk 0 into regs ----
    #pragma unroll
    for (int k = 0; k < 6; ++k) {
        const int i = tid + k * 256;
        rv[k] = (int4v){0, 0, 0, 0};
        if (i < 1296) {
            int p = i >> 2, q = i & 3;
            int hy = p / 18, hx = p - hy * 18;
            int gy = ty0 + hy - 1, gx = tx0 + hx - 1;
            if (gy >= 0 && gy < H && gx >= 0 && gx < W) {
                long pg = (long)(b * H + gy) * W + gx;
                rv[k] = *(const int4v*)(fhl + (0 * npx + pg) * 32 + q * 8);
            }
        }
    }

    for (int c = 0; c < NCHUNK; ++c) {
        __syncthreads();   // prior chunk's MFMA done reading LDS
        // ---- write prefetched regs -> LDS ----
        #pragma unroll
        for (int k = 0; k < 6; ++k) {
            const int i = tid + k * 256;
            if (i < 1296) {
                int p = i >> 2, q = i & 3;
                char* dst = (q < 2) ? (char*)hi_t + p * 48 + q * 16
                                    : (char*)lo_t + p * 48 + (q - 2) * 16;
                *(int4v*)dst = rv[k];
            }
        }
        __syncthreads();
        // ---- issue next chunk's loads (latency hides under MFMA below) ----
        if (c + 1 < NCHUNK) {
            #pragma unroll
            for (int k = 0; k < 6; ++k) {
                const int i = tid + k * 256;
                rv[k] = (int4v){0, 0, 0, 0};
                if (i < 1296) {
                    int p = i >> 2, q = i & 3;
                    int hy = p / 18, hx = p - hy * 18;
                    int gy = ty0 + hy - 1, gx = tx0 + hx - 1;
                    if (gy >= 0 && gy < H && gx >= 0 && gx < W) {
                        long pg = (long)(b * H + gy) * W + gx;
                        rv[k] = *(const int4v*)(fhl + ((long)(c + 1) * npx + pg) * 32 + q * 8);
                    }
                }
            }
        }

        const char* ahc = aph + (long)c * 9216;
        const char* alc = apl + (long)c * 9216;
        #pragma unroll
        for (int s = 0; s < 9; ++s) {
            const int dy = s / 3, dx = s % 3;
            const int p0 = (ly0 + dy) * 18 + (lx + dx);
            const int p1 = p0 + 36;
            short8v bh0 = *(const short8v*)((const char*)hi_t + p0 * 48 + h * 16);
            short8v bh1 = *(const short8v*)((const char*)hi_t + p1 * 48 + h * 16);
            short8v bl0 = *(const short8v*)((const char*)lo_t + p0 * 48 + h * 16);
            short8v bl1 = *(const short8v*)((const char*)lo_t + p1 * 48 + h * 16);
            #pragma unroll
            for (int cg = 0; cg < 2; ++cg) {
                short8v af = *(const short8v*)(ahc + cg * cgstride + s * 1024);
                short8v al = *(const short8v*)(alc + cg * cgstride + s * 1024);
                acc[cg][0] = __builtin_amdgcn_mfma_f32_32x32x16_bf16(af, bh0, acc[cg][0], 0, 0, 0);
                acc[cg][0] = __builtin_amdgcn_mfma_f32_32x32x16_bf16(af, bl0, acc[cg][0], 0, 0, 0);
                acc[cg][0] = __builtin_amdgcn_mfma_f32_32x32x16_bf16(al, bh0, acc[cg][0], 0, 0, 0);
                acc[cg][1] = __builtin_amdgcn_mfma_f32_32x32x16_bf16(af, bh1, acc[cg][1], 0, 0, 0);
                acc[cg][1] = __builtin_amdgcn_mfma_f32_32x32x16_bf16(af, bl1, acc[cg][1], 0, 0, 0);
                acc[cg][1] = __builtin_amdgcn_mfma_f32_32x32x16_bf16(al, bh1, acc[cg][1], 0, 0, 0);
            }
        }
    }
    __syncthreads();   // last MFMA done before sbuf reuse

    // ---- epilogue: LIF -> LDS transpose -> coalesced 16B stores ----
    for (int i = tid; i < 1280; i += 256)
        *(int4v*)((char*)sbuf + i * 16) = (int4v){0, 0, 0, 0};
    __syncthreads();

    #pragma unroll
    for (int cg = 0; cg < 2; ++cg) {
        #pragma unroll
        for (int r = 0; r < 16; ++r) {
            const int co = (cg << 5) + (r & 3) + ((r >> 2) << 3) + (h << 2);
            if (co < 36) {
                const float sc   = bn_s[co], sb = bn_b[co];
                const float beta = 1.f / (1.f + expf(-beta_raw[co]));
                const float t    = thr[co];
                #pragma unroll
                for (int pf = 0; pf < 2; ++pf) {
                    const int ly = ly0 + pf * 2;
                    float hv = acc[cg][pf][r] * sc + sb;
                    float m = 0.f, c2 = 0.f;
                    #pragma unroll
                    for (int s4 = 0; s4 < 4; ++s4) {
                        m = beta * m + hv;
                        if (m > t) { c2 += 1.f; m -= t; }
                    }
                    __hip_bfloat16 ov = __float2bfloat16(c2 * 0.25f);
                    sbuf[(ly * 16 + lx) * 40 + co] = *(short*)&ov;
                }
            }
        }
    }
    __syncthreads();

    const long tilebase = ((long)(b * H + ty0) * W + tx0) * 40;
    for (int i = tid; i < 1280; i += 256) {
        int px = i / 5, u = i - px * 5;
        int py2 = px >> 4, px2 = px & 15;
        *(int4v*)(avg + tilebase + ((long)py2 * W + px2) * 40 + u * 8) =
            *(const int4v*)(sbuf + px * 40 + u * 8);
    }
}

// ===========================================================================
// MFMA encoder, ci-split partial variant (enc5), same reg-prefetch pipeline.
// ===========================================================================
template<int CIN, int CIPER>
__global__ __launch_bounds__(256) void enc_mfma_p(
    const __hip_bfloat16* __restrict__ fhl,
    const __hip_bfloat16* __restrict__ whi,
    const __hip_bfloat16* __restrict__ wlo,
    float* __restrict__ partial,
    int H, int W, int tiles_x)
{
    const int NCH_TOT = CIN / 16;
    const int NCH_PER = CIPER / 16;
    __shared__ __align__(16) short sbuf[324 * 48];
    short* hi_t = sbuf;
    short* lo_t = sbuf + 324 * 24;

    const int tid = threadIdx.x;
    const int b   = blockIdx.y;
    const int cis = blockIdx.z;
    const int tx0 = (blockIdx.x % tiles_x) * 16;
    const int ty0 = (blockIdx.x / tiles_x) * 16;
    const long npx = (long)16 * H * W;

    const int lane = tid & 63;
    const int wv   = tid >> 6;
    const int h    = lane >> 5;
    const int n    = lane & 31;
    const int lx   = n & 15;
    const int ly0  = wv * 4 + (n >> 4);

    f32x16 acc[2][2];
    #pragma unroll
    for (int cg = 0; cg < 2; ++cg)
        #pragma unroll
        for (int pf = 0; pf < 2; ++pf)
            #pragma unroll
            for (int k = 0; k < 16; ++k) acc[cg][pf][k] = 0.f;

    const char* aph = (const char*)whi + h * 512 + n * 16;
    const char* apl = (const char*)wlo + h * 512 + n * 16;
    const long  cgstride = (long)NCH_TOT * 9216;

    int4v rv[6];
    #pragma unroll
    for (int k = 0; k < 6; ++k) {
        const int i = tid + k * 256;
        rv[k] = (int4v){0, 0, 0, 0};
        if (i < 1296) {
            int p = i >> 2, q = i & 3;
            int hy = p / 18, hx = p - hy * 18;
            int gy = ty0 + hy - 1, gx = tx0 + hx - 1;
            if (gy >= 0 && gy < H && gx >= 0 && gx < W) {
                long pg = (long)(b * H + gy) * W + gx;
                rv[k] = *(const int4v*)(fhl + ((long)(cis * NCH_PER) * npx + pg) * 32 + q * 8);
            }
        }
    }

    for (int c = 0; c < NCH_PER; ++c) {
        const int gc = cis * NCH_PER + c;
        __syncthreads();
        #pragma unroll
        for (int k = 0; k < 6; ++k) {
            const int i = tid + k * 256;
            if (i < 1296) {
                int p = i >> 2, q = i & 3;
                char* dst = (q < 2) ? (char*)hi_t + p * 48 + q * 16
                                    : (char*)lo_t + p * 48 + (q - 2) * 16;
                *(int4v*)dst = rv[k];
            }
        }
        __syncthreads();
        if (c + 1 < NCH_PER) {
            #pragma unroll
            for (int k = 0; k < 6; ++k) {
                const int i = tid + k * 256;
                rv[k] = (int4v){0, 0, 0, 0};
                if (i < 1296) {
                    int p = i >> 2, q = i & 3;
                    int hy = p / 18, hx = p - hy * 18;
                    int gy = ty0 + hy - 1, gx = tx0 + hx - 1;
                    if (gy >= 0 && gy < H && gx >= 0 && gx < W) {
                        long pg = (long)(b * H + gy) * W + gx;
                        rv[k] = *(const int4v*)(fhl + ((long)(gc + 1) * npx + pg) * 32 + q * 8);
                    }
                }
            }
        }

        const char* ahc = aph + (long)gc * 9216;
        const char* alc = apl + (long)gc * 9216;
        #pragma unroll
        for (int s = 0; s < 9; ++s) {
            const int dy = s / 3, dx = s % 3;
            const int p0 = (ly0 + dy) * 18 + (lx + dx);
            const int p1 = p0 + 36;
            short8v bh0 = *(const short8v*)((const char*)hi_t + p0 * 48 + h * 16);
            short8v bh1 = *(const short8v*)((const char*)hi_t + p1 * 48 + h * 16);
            short8v bl0 = *(const short8v*)((const char*)lo_t + p0 * 48 + h * 16);
            short8v bl1 = *(const short8v*)((const char*)lo_t + p1 * 48 + h * 16);
            #pragma unroll
            for (int cg = 0; cg < 2; ++cg) {
                short8v af = *(const short8v*)(ahc + cg * cgstride + s * 1024);
                short8v al = *(const short8v*)(alc + cg * cgstride + s * 1024);
                acc[cg][0] = __builtin_amdgcn_mfma_f32_32x32x16_bf16(af, bh0, acc[cg][0], 0, 0, 0);
                acc[cg][0] = __builtin_amdgcn_mfma_f32_32x32x16_bf16(af, bl0, acc[cg][0], 0, 0, 0);
                acc[cg][0] = __builtin_amdgcn_mfma_f32_32x32x16_bf16(al, bh0, acc[cg][0], 0, 0, 0);
                acc[cg][1] = __builtin_amdgcn_mfma_f32_32x32x16_bf16(af, bh1, acc[cg][1], 0, 0, 0);
                acc[cg][1] = __builtin_amdgcn_mfma_f32_32x32x16_bf16(af, bl1, acc[cg][1], 0, 0, 0);
                acc[cg][1] = __builtin_amdgcn_mfma_f32_32x32x16_bf16(al, bh1, acc[cg][1], 0, 0, 0);
            }
        }
    }

    const int HW = H * W;
    const long total = (long)16 * 36 * HW;
    #pragma unroll
    for (int cg = 0; cg < 2; ++cg) {
        #pragma unroll
        for (int r = 0; r < 16; ++r) {
            const int co = (cg << 5) + (r & 3) + ((r >> 2) << 3) + (h << 2);
            if (co < 36) {
                #pragma unroll
                for (int pf = 0; pf < 2; ++pf) {
                    const int gy = ty0 + ly0 + pf * 2, gx = tx0 + lx;
                    if (gy < H && gx < W)
                        partial[(long)cis * total + ((long)(b * 36 + co) * HW + gy * W + gx)]
                            = acc[cg][pf][r];
                }
            }
        }
    }
}

// ===========================================================================
// Original encoder (fallback path).
// ===========================================================================
template<int CIN, int CIPER, int CICHUNK, int COCHUNK, int TDIM, bool PARTIAL, bool CL>
__global__ __launch_bounds__(TDIM* TDIM) void enc_tiled(
    const float* __restrict__ feat,
    const float* __restrict__ w,
    const float* __restrict__ bn_s, const float* __restrict__ bn_b,
    const float* __restrict__ thr, const float* __restrict__ beta_raw,
    __hip_bfloat16* __restrict__ avg,
    float* __restrict__ partial,
    int H, int W, int tiles_x)
{
    const int TPB  = TDIM * TDIM;
    const int HALOD = TDIM + 2;
    const int NCO  = 36 / COCHUNK;
    __shared__ float fs[CICHUNK][HALOD][HALOD];

    const int tile = blockIdx.x;
    const int b    = blockIdx.y;
    const int coc  = blockIdx.z % NCO;
    const int cis  = blockIdx.z / NCO;
    const int co0  = coc * COCHUNK;
    const int tx0  = (tile % tiles_x) * TDIM;
    const int ty0  = (tile / tiles_x) * TDIM;

    const int tx = threadIdx.x % TDIM;
    const int ty = threadIdx.x / TDIM;
    const int ox = tx0 + tx, oy = ty0 + ty;

    float acc[COCHUNK];
    #pragma unroll
    for (int c = 0; c < COCHUNK; ++c) acc[c] = 0.f;

    const float* fb = feat + (long)b * CIN * H * W;
    const int ci_base = cis * CIPER;

    for (int cc = ci_base; cc < ci_base + CIPER; cc += CICHUNK) {
        for (int i = threadIdx.x; i < CICHUNK * HALOD * HALOD; i += TPB) {
            int ci = i / (HALOD * HALOD);
            int r  = i % (HALOD * HALOD);
            int hy = r / HALOD, hx = r % HALOD;
            int gy = ty0 + hy - 1, gx = tx0 + hx - 1;
            float v = 0.f;
            if (gy >= 0 && gy < H && gx >= 0 && gx < W)
                v = fb[((long)(cc + ci) * H + gy) * W + gx];
            fs[ci][hy][hx] = v;
        }
        __syncthreads();

        for (int ci = 0; ci < CICHUNK; ++ci) {
            float f0 = fs[ci][ty    ][tx], f1 = fs[ci][ty    ][tx+1], f2 = fs[ci][ty    ][tx+2];
            float f3 = fs[ci][ty + 1][tx], f4 = fs[ci][ty + 1][tx+1], f5 = fs[ci][ty + 1][tx+2];
            float f6 = fs[ci][ty + 2][tx], f7 = fs[ci][ty + 2][tx+1], f8 = fs[ci][ty + 2][tx+2];
            const float* wq = w + (long)(cc + ci) * 9;
            #pragma unroll
            for (int j = 0; j < COCHUNK; ++j) {
                const float* ww = wq + (long)(co0 + j) * CIN * 9;
                acc[j] += f0 * ww[0] + f1 * ww[1] + f2 * ww[2]
                        + f3 * ww[3] + f4 * ww[4] + f5 * ww[5]
                        + f6 * ww[6] + f7 * ww[7] + f8 * ww[8];
            }
        }
        __syncthreads();
    }

    if (ox < W && oy < H) {
        if (PARTIAL) {
            #pragma unroll
            for (int j = 0; j < COCHUNK; ++j)
                partial[((((long)cis * 16 + b) * 36 + (co0 + j)) * H + oy) * W + ox] = acc[j];
        } else {
            float cnt[COCHUNK];
            #pragma unroll
            for (int j = 0; j < COCHUNK; ++j) {
                int co = co0 + j;
                float hh   = acc[j] * bn_s[co] + bn_b[co];
                float beta = 1.f / (1.f + expf(-beta_raw[co]));
                float t    = thr[co];
                float m = 0.f, c2 = 0.f;
                #pragma unroll
                for (int s = 0; s < 4; ++s) {
                    m = beta * m + hh;
                    if (m > t) { c2 += 1.f; m -= t; }
                }
                cnt[j] = c2 * 0.25f;
            }
            if (CL) {
                unsigned* dp = (unsigned*)(avg + ((long)(b * H + oy) * W + ox) * 40 + co0);
                #pragma unroll
                for (int j2 = 0; j2 < COCHUNK / 2; ++j2) {
                    __hip_bfloat16 h0 = __float2bfloat16(cnt[2 * j2]);
                    __hip_bfloat16 h1 = __float2bfloat16(cnt[2 * j2 + 1]);
                    unsigned u0 = *(unsigned short*)&h0;
                    unsigned u1 = *(unsigned short*)&h1;
                    dp[j2] = u0 | (u1 << 16);
                }
            } else {
                #pragma unroll
                for (int j = 0; j < COCHUNK; ++j)
                    avg[(((long)b * 36 + (co0 + j)) * H + oy) * W + ox] = __float2bfloat16(cnt[j]);
            }
        }
    }
}

// ===========================================================================
// Combine ci-split partials + BN + LIF + mean -> bf16 avg (CL or NCHW).
// ===========================================================================
template<int SPLITS, bool CL>
__global__ __launch_bounds__(256) void combine_lif(
    const float* __restrict__ partial,
    const float* __restrict__ bn_s, const float* __restrict__ bn_b,
    const float* __restrict__ thr, const float* __restrict__ beta_raw,
    __hip_bfloat16* __restrict__ avg, int H, int W, int total)
{
    int idx = blockIdx.x * 256 + threadIdx.x;
    if (idx >= total) return;
    int HW = H * W;
    int co = (idx / HW) % 36;
    float hh = 0.f;
    #pragma unroll
    for (int s = 0; s < SPLITS; ++s) hh += partial[(long)s * total + idx];
    hh = hh * bn_s[co] + bn_b[co];
    float beta = 1.f / (1.f + expf(-beta_raw[co]));
    float t    = thr[co];
    float m = 0.f, cnt = 0.f;
    #pragma unroll
    for (int s = 0; s < 4; ++s) {
        m = beta * m + hh;
        if (m > t) { cnt += 1.f; m -= t; }
    }
    if (CL) {
        int b = idx / (36 * HW);
        int rem = idx % HW;
        int y = rem / W, x = rem % W;
        avg[((long)(b * H + y) * W + x) * 40 + co] = __float2bfloat16(cnt * 0.25f);
    } else {
        avg[idx] = __float2bfloat16(cnt * 0.25f);
    }
}

// ===========================================================================
// Weight prepack for MFMA decoder.
// ===========================================================================
__global__ __launch_bounds__(256) void pack_w(
    const float* __restrict__ w, __hip_bfloat16* __restrict__ ap, int total)
{
    int idx = blockIdx.x * 256 + threadIdx.x;
    if (idx >= total) return;
    int m  = idx & 31;
    int h  = (idx >> 5) & 1;
    int s  = (idx >> 6) % 23;
    int cg = idx / (23 * 64);
    int o  = 2 * s + h;
    int co = cg * 32 + m;
    unsigned short v[8];
    #pragma unroll
    for (int j = 0; j < 8; ++j) {
        float x = 0.f;
        if (o < 45) {
            int tap = o / 5, oct = o % 5, ci = oct * 8 + j;
            if (ci < 36) x = w[(long)co * 324 + ci * 9 + tap];
        }
        __hip_bfloat16 hv = __float2bfloat16(x);
        v[j] = *(unsigned short*)&hv;
    }
    *(int4v*)(ap + (long)idx * 8) = *(int4v*)v;
}

// ===========================================================================
// MFMA decoder: conv3x3(36->Cout) + BN + SiLU.
// ===========================================================================
template<int COG>
__global__ __launch_bounds__(256) void dec_mfma(
    const __hip_bfloat16* __restrict__ avg_cl,
    const __hip_bfloat16* __restrict__ apack,
    const float* __restrict__ bn_s, const float* __restrict__ bn_b,
    float* __restrict__ out, int Cout, int H, int W, int tiles_x)
{
    __shared__ __hip_bfloat16 tile[12960];

    const int tid    = threadIdx.x;
    const int b      = blockIdx.y;
    const int cgbase = blockIdx.z * COG;
    const int tx0 = (blockIdx.x % tiles_x) * 16;
    const int ty0 = (blockIdx.x / tiles_x) * 16;

    {
        const __hip_bfloat16* ab = avg_cl + (long)b * H * W * 40;
        for (int i = tid; i < 1620; i += 256) {
            int row = i / 90, u = i - row * 90;
            int px = u / 5, un = u - px * 5;
            int gy = ty0 + row - 1, gx = tx0 + px - 1;
            int4v v = {0, 0, 0, 0};
            if (gy >= 0 && gy < H && gx >= 0 && gx < W)
                v = *(const int4v*)(ab + ((long)gy * W + gx) * 40 + un * 8);
            *(int4v*)(tile + (row * 18 + px) * 40 + un * 8) = v;
        }
    }
    __syncthreads();

    const int lane = tid & 63;
    const int wv   = tid >> 6;
    const int h    = lane >> 5;
    const int n    = lane & 31;
    const int lx   = n & 15;
    const int ly0  = wv * 4 + (n >> 4);

    const char* tb  = (const char*)tile;
    const int   bb0 = ((ly0 + 1) * 18 + (lx + 1)) * 80;
    const int   bb1 = bb0 + 2 * 18 * 80;

    const char* ap = (const char*)apack + (long)cgbase * 23552 + h * 512 + n * 16;

    f32x16 acc[COG][2];
    #pragma unroll
    for (int cg = 0; cg < COG; ++cg)
        #pragma unroll
        for (int pf = 0; pf < 2; ++pf)
            #pragma unroll
            for (int k = 0; k < 16; ++k) acc[cg][pf][k] = 0.f;

    #pragma unroll
    for (int s = 0; s < 23; ++s) {
        int o0 = 2 * s;     if (o0 > 44) o0 = 44;
        int o1 = 2 * s + 1; if (o1 > 44) o1 = 44;
        const int C0 = ((o0 / 5) / 3 - 1) * 1440 + ((o0 / 5) % 3 - 1) * 80 + (o0 % 5) * 16;
        const int C1 = ((o1 / 5) / 3 - 1) * 1440 + ((o1 / 5) % 3 - 1) * 80 + (o1 % 5) * 16;
        const int offc = h ? C1 : C0;
        short8v bf0 = *(const short8v*)(tb + (bb0 + offc));
        short8v bf1 = *(const short8v*)(tb + (bb1 + offc));
        #pragma unroll
        for (int cg = 0; cg < COG; ++cg) {
            short8v af = *(const short8v*)(ap + cg * 23552 + s * 1024);
            acc[cg][0] = __builtin_amdgcn_mfma_f32_32x32x16_bf16(af, bf0, acc[cg][0], 0, 0, 0);
            acc[cg][1] = __builtin_amdgcn_mfma_f32_32x32x16_bf16(af, bf1, acc[cg][1], 0, 0, 0);
        }
    }

    #pragma unroll
    for (int cg = 0; cg < COG; ++cg) {
        #pragma unroll
        for (int r = 0; r < 16; ++r) {
            const int co = ((cgbase + cg) << 5) + (r & 3) + ((r >> 2) << 3) + (h << 2);
            const float sc = bn_s[co], bc = bn_b[co];
            #pragma unroll
            for (int pf = 0; pf < 2; ++pf) {
                const int ly = ly0 + pf * 2;
                const int gy = ty0 + ly, gx = tx0 + lx;
                float v = acc[cg][pf][r] * sc + bc;
                v = v / (1.f + __expf(-v));
                if (gy < H && gx < W)
                    out[(((long)b * Cout + co) * H + gy) * W + gx] = v;
            }
        }
    }
}

// ===========================================================================
// Fallback decoder (VALU, NCHW avg).
// ===========================================================================
template<int COCHUNK, int TDIM>
__global__ __launch_bounds__(TDIM* TDIM) void dec_tiled(
    const __hip_bfloat16* __restrict__ avg,
    const float* __restrict__ w,
    const float* __restrict__ bn_s, const float* __restrict__ bn_b,
    float* __restrict__ out,
    int Cout, int H, int W, int tiles_x)
{
    const int CIN = 36;
    const int TPB = TDIM * TDIM;
    const int HALOD = TDIM + 2;
    __shared__ float fs[CIN][HALOD][HALOD];

    const int tile = blockIdx.x;
    const int b    = blockIdx.y;
    const int co0  = blockIdx.z * COCHUNK;
    const int tx0  = (tile % tiles_x) * TDIM;
    const int ty0  = (tile / tiles_x) * TDIM;

    const int tx = threadIdx.x % TDIM;
    const int ty = threadIdx.x / TDIM;
    const int ox = tx0 + tx, oy = ty0 + ty;

    const __hip_bfloat16* ab = avg + (long)b * CIN * H * W;

    for (int i = threadIdx.x; i < CIN * HALOD * HALOD; i += TPB) {
        int ci = i / (HALOD * HALOD);
        int r  = i % (HALOD * HALOD);
        int hy = r / HALOD, hx = r % HALOD;
        int gy = ty0 + hy - 1, gx = tx0 + hx - 1;
        float v = 0.f;
        if (gy >= 0 && gy < H && gx >= 0 && gx < W)
            v = __bfloat162float(ab[((long)ci * H + gy) * W + gx]);
        fs[ci][hy][hx] = v;
    }
    __syncthreads();

    float acc[COCHUNK];
    #pragma unroll
    for (int j = 0; j < COCHUNK; ++j) acc[j] = 0.f;

    for (int ci = 0; ci < CIN; ++ci) {
        float f0 = fs[ci][ty    ][tx], f1 = fs[ci][ty    ][tx+1], f2 = fs[ci][ty    ][tx+2];
        float f3 = fs[ci][ty + 1][tx], f4 = fs[ci][ty + 1][tx+1], f5 = fs[ci][ty + 1][tx+2];
        float f6 = fs[ci][ty + 2][tx], f7 = fs[ci][ty + 2][tx+1], f8 = fs[ci][ty + 2][tx+2];
        #pragma unroll
        for (int j = 0; j < COCHUNK; ++j) {
            const float* ww = w + ((long)(co0 + j) * CIN + ci) * 9;
            acc[j] += f0 * ww[0] + f1 * ww[1] + f2 * ww[2]
                    + f3 * ww[3] + f4 * ww[4] + f5 * ww[5]
                    + f6 * ww[6] + f7 * ww[7] + f8 * ww[8];
        }
    }

    if (ox < W && oy < H) {
        #pragma unroll
        for (int j = 0; j < COCHUNK; ++j) {
            int co = co0 + j;
            float v = acc[j] * bn_s[co] + bn_b[co];
            out[(((long)b * Cout + co) * H + oy) * W + ox] = v / (1.f + expf(-v));
        }
    }
}

// ===========================================================================
extern "C" void kernel_launch(void* const* d_in, const int* in_sizes, int n_in,
                              void* d_out, int out_size, void* d_ws, size_t ws_size,
                              hipStream_t stream)
{
    const int B = 16;
    const int C[3] = {64, 128, 256};
    const int S[3] = {160, 80, 40};

    float* out = (float*)d_out;
    long out_off[3]; long off = 0;
    for (int l = 0; l < 3; ++l) { out_off[l] = off; off += (long)B * C[l] * S[l] * S[l]; }

    // ---- workspace layout (bytes) ----
    const long avgcl_bytes[3] = {32768000L, 8192000L, 2048000L};
    long avgcl_off[3]; long boff = 0;
    for (int l = 0; l < 3; ++l) { avgcl_off[l] = boff; boff += avgcl_bytes[l]; }
    const long avgcl_total = boff;
    const long ap_bytes[3] = {47104L, 94208L, 188416L};
    long ap_off[3];
    for (int l = 0; l < 3; ++l) { ap_off[l] = boff; boff += ap_bytes[l]; }
    const long we_bytes[3] = {73728L, 147456L, 294912L};
    long wehi_off[3], welo_off[3];
    for (int l = 0; l < 3; ++l) { wehi_off[l] = boff; boff += we_bytes[l];
                                  welo_off[l] = boff; boff += we_bytes[l]; }
    const long part5_off = boff;
    const long part5_bytes = 4L * B * 36 * 1600 * 4;
    boff += part5_bytes;
    const size_t need_full = (size_t)boff;
    const size_t need_min  = (size_t)part5_off;
    const long fhl_bytes[3] = {104857600L, 52428800L, 26214400L};
    long fhl_off[3];
    for (int l = 0; l < 2; ++l) { fhl_off[l] = boff; boff += fhl_bytes[l]; }
    const size_t need_cl = (size_t)boff;
    fhl_off[2] = boff; boff += fhl_bytes[2];
    const size_t need_cl5 = (size_t)boff;

    char* wsb = (char*)d_ws;

    if (ws_size >= need_min) {
        const bool split5  = ws_size >= need_full;
        const bool use_cl  = ws_size >= need_cl;
        const bool use_cl5 = ws_size >= need_cl5;
        hipMemsetAsync(wsb, 0, avgcl_total, stream);

        for (int l = 0; l < 3; ++l) {
            const float* dec_w = (const float*)d_in[9 * l + 6];
            int total = (C[l] / 32) * 23 * 2 * 32;
            pack_w<<<(total + 255) / 256, 256, 0, stream>>>(
                dec_w, (__hip_bfloat16*)(wsb + ap_off[l]), total);
        }
        {
            const float* enc_w3 = (const float*)d_in[1];
            int total = 2 * (64 / 16) * 9 * 2 * 32;
            pack_we<64><<<(total + 255) / 256, 256, 0, stream>>>(
                enc_w3, (__hip_bfloat16*)(wsb + wehi_off[0]),
                (__hip_bfloat16*)(wsb + welo_off[0]), total);
        }
        {
            const float* enc_w4 = (const float*)d_in[10];
            int total = 2 * (128 / 16) * 9 * 2 * 32;
            pack_we<128><<<(total + 255) / 256, 256, 0, stream>>>(
                enc_w4, (__hip_bfloat16*)(wsb + wehi_off[1]),
                (__hip_bfloat16*)(wsb + welo_off[1]), total);
        }
        if (use_cl5) {
            const float* enc_w5 = (const float*)d_in[19];
            int total = 2 * (256 / 16) * 9 * 2 * 32;
            pack_we<256><<<(total + 255) / 256, 256, 0, stream>>>(
                enc_w5, (__hip_bfloat16*)(wsb + wehi_off[2]),
                (__hip_bfloat16*)(wsb + welo_off[2]), total);
        }
        if (use_cl) {
            {
                int HW = 160 * 160, npx = B * HW;
                feat_hl<64, 64><<<(npx + 63) / 64, 256, 0, stream>>>(
                    (const float*)d_in[0], (__hip_bfloat16*)(wsb + fhl_off[0]), HW, npx);
            }
            {
                int HW = 80 * 80, npx = B * HW;
                feat_hl<128, 64><<<(npx + 63) / 64, 256, 0, stream>>>(
                    (const float*)d_in[9], (__hip_bfloat16*)(wsb + fhl_off[1]), HW, npx);
            }
        }
        if (use_cl5) {
            int HW = 40 * 40, npx = B * HW;
            feat_hl<256, 32><<<(npx + 31) / 32, 256, 0, stream>>>(
                (const float*)d_in[18], (__hip_bfloat16*)(wsb + fhl_off[2]), HW, npx);
        }

        for (int l = 0; l < 3; ++l) {
            const int base = 9 * l;
            const float* feat     = (const float*)d_in[base + 0];
            const float* enc_w    = (const float*)d_in[base + 1];
            const float* enc_bn_s = (const float*)d_in[base + 2];
            const float* enc_bn_b = (const float*)d_in[base + 3];
            const float* enc_thr  = (const float*)d_in[base + 4];
            const float* enc_beta = (const float*)d_in[base + 5];
            const float* dec_bn_s = (const float*)d_in[base + 7];
            const float* dec_bn_b = (const float*)d_in[base + 8];

            const int Hs = S[l], Wsz = S[l];
            __hip_bfloat16* avg_cl = (__hip_bfloat16*)(wsb + avgcl_off[l]);
            const __hip_bfloat16* ap = (const __hip_bfloat16*)(wsb + ap_off[l]);
            float* r = out + out_off[l];

            if (l == 0) {
                dim3 eg(100, B);
                if (use_cl)
                    enc_mfma_cl<64><<<eg, 256, 0, stream>>>(
                        (const __hip_bfloat16*)(wsb + fhl_off[0]),
                        (const __hip_bfloat16*)(wsb + wehi_off[0]),
                        (const __hip_bfloat16*)(wsb + welo_off[0]),
                        enc_bn_s, enc_bn_b, enc_thr, enc_beta, avg_cl, Hs, Wsz, 10);
                else
                    enc_tiled<64, 64, 16, 12, 16, false, true><<<dim3(100, B, 3), 256, 0, stream>>>(
                        feat, enc_w, enc_bn_s, enc_bn_b, enc_thr, enc_beta, avg_cl, nullptr, Hs, Wsz, 10);
                dim3 dg(100, B, 1);
                dec_mfma<2><<<dg, 256, 0, stream>>>(avg_cl, ap, dec_bn_s, dec_bn_b, r, 64, Hs, Wsz, 10);
            } else if (l == 1) {
                dim3 eg(25, B);
                if (use_cl)
                    enc_mfma_cl<128><<<eg, 256, 0, stream>>>(
                        (const __hip_bfloat16*)(wsb + fhl_off[1]),
                        (const __hip_bfloat16*)(wsb + wehi_off[1]),
                        (const __hip_bfloat16*)(wsb + welo_off[1]),
                        enc_bn_s, enc_bn_b, enc_thr, enc_beta, avg_cl, Hs, Wsz, 5);
                else
                    enc_tiled<128, 128, 16, 12, 16, false, true><<<dim3(25, B, 3), 256, 0, stream>>>(
                        feat, enc_w, enc_bn_s, enc_bn_b, enc_thr, enc_beta, avg_cl, nullptr, Hs, Wsz, 5);
                dim3 dg(25, B, 2);
                dec_mfma<2><<<dg, 256, 0, stream>>>(avg_cl, ap, dec_bn_s, dec_bn_b, r, 128, Hs, Wsz, 5);
            } else {
                if (use_cl5) {
                    float* partial5 = (float*)(wsb + part5_off);
                    dim3 eg(9, B, 4);
                    enc_mfma_p<256, 64><<<eg, 256, 0, stream>>>(
                        (const __hip_bfloat16*)(wsb + fhl_off[2]),
                        (const __hip_bfloat16*)(wsb + wehi_off[2]),
                        (const __hip_bfloat16*)(wsb + welo_off[2]),
                        partial5, Hs, Wsz, 3);
                    int total = B * 36 * Hs * Wsz;
                    combine_lif<4, true><<<(total + 255) / 256, 256, 0, stream>>>(
                        partial5, enc_bn_s, enc_bn_b, enc_thr, enc_beta, avg_cl, Hs, Wsz, total);
                } else if (split5) {
                    float* partial5 = (float*)(wsb + part5_off);
                    dim3 eg(25, B, 12);
                    enc_tiled<256, 64, 16, 12, 8, true, true><<<eg, 64, 0, stream>>>(
                        feat, enc_w, enc_bn_s, enc_bn_b, enc_thr, enc_beta, nullptr, partial5, Hs, Wsz, 5);
                    int total = B * 36 * Hs * Wsz;
                    combine_lif<4, true><<<(total + 255) / 256, 256, 0, stream>>>(
                        partial5, enc_bn_s, enc_bn_b, enc_thr, enc_beta, avg_cl, Hs, Wsz, total);
                } else {
                    dim3 eg(25, B, 3);
                    enc_tiled<256, 256, 16, 12, 8, false, true><<<eg, 64, 0, stream>>>(
                        feat, enc_w, enc_bn_s, enc_bn_b, enc_thr, enc_beta, avg_cl, nullptr, Hs, Wsz, 5);
                }
                dim3 dg(9, B, 4);
                dec_mfma<2><<<dg, 256, 0, stream>>>(avg_cl, ap, dec_bn_s, dec_bn_b, r, 256, Hs, Wsz, 3);
            }
        }
    } else {
        // ================= FALLBACK (NCHW, VALU decoder) =================
        __hip_bfloat16* ws = (__hip_bfloat16*)d_ws;
        long avg_off2[3]; long eoff = 0;
        for (int l = 0; l < 3; ++l) { avg_off2[l] = eoff; eoff += (long)B * 36 * S[l] * S[l]; }
        float* partial5 = (float*)(ws + ((eoff + 7) & ~7L));
        const long part5f = 4L * B * 36 * 40 * 40;
        const size_t old_need = (size_t)((eoff + 7) & ~7L) * 2 + part5f * 4;
        const bool split5 = ws_size >= old_need;

        for (int l = 0; l < 3; ++l) {
            const int base = 9 * l;
            const float* feat     = (const float*)d_in[base + 0];
            const float* enc_w    = (const float*)d_in[base + 1];
            const float* enc_bn_s = (const float*)d_in[base + 2];
            const float* enc_bn_b = (const float*)d_in[base + 3];
            const float* enc_thr  = (const float*)d_in[base + 4];
            const float* enc_beta = (const float*)d_in[base + 5];
            const float* dec_w    = (const float*)d_in[base + 6];
            const float* dec_bn_s = (const float*)d_in[base + 7];
            const float* dec_bn_b = (const float*)d_in[base + 8];

            const int Hs = S[l], Wsz = S[l], Cl = C[l];
            __hip_bfloat16* avg = ws + avg_off2[l];
            float* r = out + out_off[l];

            if (l == 0) {
                dim3 eg(100, B, 3);
                enc_tiled<64, 64, 16, 12, 16, false, false><<<eg, 256, 0, stream>>>(
                    feat, enc_w, enc_bn_s, enc_bn_b, enc_thr, enc_beta, avg, nullptr, Hs, Wsz, 10);
                dim3 dg(100, B, 2);
                dec_tiled<32, 16><<<dg, 256, 0, stream>>>(avg, dec_w, dec_bn_s, dec_bn_b, r, Cl, Hs, Wsz, 10);
            } else if (l == 1) {
                dim3 eg(25, B, 3);
                enc_tiled<128, 128, 16, 12, 16, false, false><<<eg, 256, 0, stream>>>(
                    feat, enc_w, enc_bn_s, enc_bn_b, enc_thr, enc_beta, avg, nullptr, Hs, Wsz, 5);
                dim3 dg(25, B, 4);
                dec_tiled<32, 16><<<dg, 256, 0, stream>>>(avg, dec_w, dec_bn_s, dec_bn_b, r, Cl, Hs, Wsz, 5);
            } else {
                if (split5) {
                    dim3 eg(25, B, 12);
                    enc_tiled<256, 64, 16, 12, 8, true, false><<<eg, 64, 0, stream>>>(
                        feat, enc_w, enc_bn_s, enc_bn_b, enc_thr, enc_beta, nullptr, partial5, Hs, Wsz, 5);
                    int total = B * 36 * Hs * Wsz;
                    combine_lif<4, false><<<(total + 255) / 256, 256, 0, stream>>>(
                        partial5, enc_bn_s, enc_bn_b, enc_thr, enc_beta, avg, Hs, Wsz, total);
                } else {
                    dim3 eg(25, B, 3);
                    enc_tiled<256, 256, 16, 12, 8, false, false><<<eg, 64, 0, stream>>>(
                        feat, enc_w, enc_bn_s, enc_bn_b, enc_thr, enc_beta, avg, nullptr, Hs, Wsz, 5);
                }
                dim3 dg(25, B, 16);
                dec_tiled<16, 8><<<dg, 64, 0, stream>>>(avg, dec_w, dec_bn_s, dec_bn_b, r, Cl, Hs, Wsz, 5);
            }
        }
    }
}